// Round 1
// baseline (395.910 us; speedup 1.0000x reference)
//
#include <hip/hip_runtime.h>
#include <hip/hip_bf16.h>
#include <cstdint>

// Problem constants
#define B_ 4
#define S_ 4096
#define D_ 1024
#define DFF_ 4096
#define KSEL_ 2048
#define M_ (B_ * KSEL_)      // 8192 selected rows total
#define NTOK_ (B_ * S_)      // 16384

typedef short bf16x8 __attribute__((ext_vector_type(8)));
typedef float f32x4 __attribute__((ext_vector_type(4)));

__device__ inline unsigned short f2bf(float f) {
    union { float f; unsigned int u; } c; c.f = f;
    unsigned int u = c.u;
    unsigned int r = u + 0x7fffu + ((u >> 16) & 1u);
    return (unsigned short)(r >> 16);
}

// ---------------------------------------------------------------------------
// Transpose + fp32->bf16 convert: src [R][C] f32 -> dst [C][R] bf16
// ---------------------------------------------------------------------------
__global__ __launch_bounds__(256)
void transpose_bf16(const float* __restrict__ src, unsigned short* __restrict__ dst,
                    int R, int C) {
    __shared__ float tile[32][33];
    int c0 = blockIdx.x * 32, r0 = blockIdx.y * 32;
    for (int i = threadIdx.y; i < 32; i += 8)
        tile[i][threadIdx.x] = src[(size_t)(r0 + i) * C + c0 + threadIdx.x];
    __syncthreads();
    for (int i = threadIdx.y; i < 32; i += 8)
        dst[(size_t)(c0 + i) * R + r0 + threadIdx.x] = f2bf(tile[threadIdx.x][i]);
}

// ---------------------------------------------------------------------------
// Router: logits[row] = dot(x[row], Wr); write xb = bf16(x); write out = x
// ---------------------------------------------------------------------------
__global__ __launch_bounds__(256)
void router_kernel(const float* __restrict__ x, const float* __restrict__ Wr,
                   float* __restrict__ logits, unsigned short* __restrict__ xb,
                   float* __restrict__ out) {
    int wid = threadIdx.x >> 6, lane = threadIdx.x & 63;
    int row = blockIdx.x * 4 + wid;
    const float* xr = x + (size_t)row * D_;
    unsigned short* xbr = xb + (size_t)row * D_;
    float* outr = out + (size_t)row * D_;
    float acc = 0.f;
#pragma unroll
    for (int j = 0; j < 4; j++) {
        int off = j * 256 + lane * 4;
        float4 v = *(const float4*)(xr + off);
        float4 w = *(const float4*)(Wr + off);
        acc += v.x * w.x + v.y * w.y + v.z * w.z + v.w * w.w;
        *(float4*)(outr + off) = v;
        ushort4 o;
        o.x = f2bf(v.x); o.y = f2bf(v.y); o.z = f2bf(v.z); o.w = f2bf(v.w);
        *(ushort4*)(xbr + off) = o;
    }
#pragma unroll
    for (int s = 32; s; s >>= 1) acc += __shfl_xor(acc, s);
    if (lane == 0) logits[row] = acc;
}

// ---------------------------------------------------------------------------
// Rank (split-j): partial rank over a 512-logit j-chunk, atomicAdd into rank[].
// ---------------------------------------------------------------------------
__global__ __launch_bounds__(256)
void rank_partial_kernel(const float* __restrict__ logits, int* __restrict__ rank) {
    __shared__ float lj[512];
    int b  = blockIdx.x >> 7;
    int ic = (blockIdx.x >> 3) & 15;
    int jc = blockIdx.x & 7;
    const float* L = logits + b * S_;
    for (int t = threadIdx.x; t < 512; t += 256) lj[t] = L[jc * 512 + t];
    __syncthreads();
    int i = ic * 256 + threadIdx.x;
    float li = L[i];
    int jbase = jc * 512;
    int r = 0;
    const float4* __restrict__ lj4 = (const float4*)lj;
#pragma unroll 4
    for (int q = 0; q < 128; q++) {
        float4 v = lj4[q];
        int jb = jbase + q * 4;
        r += (v.x > li) | ((v.x == li) & (jb     < i));
        r += (v.y > li) | ((v.y == li) & (jb + 1 < i));
        r += (v.z > li) | ((v.z == li) & (jb + 2 < i));
        r += (v.w > li) | ((v.w == li) & (jb + 3 < i));
    }
    atomicAdd(&rank[b * S_ + i], r);
}

// ---------------------------------------------------------------------------
// Compact: sel = rank < KSEL_; flags, softmax weights, prefix-sum -> rowidx/rw.
// ---------------------------------------------------------------------------
__global__ __launch_bounds__(256)
void compact_kernel(const float* __restrict__ logits, const int* __restrict__ rank,
                    int* __restrict__ flags,
                    int* __restrict__ rowidx, float* __restrict__ rw) {
    __shared__ float lg[S_];
    __shared__ int f[S_];
    __shared__ int tsum[256];
    __shared__ float red[256];
    int b = blockIdx.x;
    const float* L = logits + b * S_;
    const int* R = rank + b * S_;
    int* F = flags + b * S_;
    for (int j = threadIdx.x; j < S_ / 4; j += 256) {
        ((float4*)lg)[j] = ((const float4*)L)[j];
        int4 rk = ((const int4*)R)[j];
        int4 fl;
        fl.x = rk.x < KSEL_; fl.y = rk.y < KSEL_;
        fl.z = rk.z < KSEL_; fl.w = rk.w < KSEL_;
        ((int4*)f)[j] = fl;
        ((int4*)F)[j] = fl;
    }
    __syncthreads();
    float mx = -INFINITY;
    for (int j = threadIdx.x; j < S_; j += 256) mx = fmaxf(mx, lg[j]);
    red[threadIdx.x] = mx; __syncthreads();
    for (int s = 128; s; s >>= 1) {
        if (threadIdx.x < s) red[threadIdx.x] = fmaxf(red[threadIdx.x], red[threadIdx.x + s]);
        __syncthreads();
    }
    float m = red[0];
    __syncthreads();

    float esum = 0.f;
    int s0 = 0;
#pragma unroll
    for (int j = 0; j < 16; j++) {
        int i = threadIdx.x * 16 + j;
        s0 += f[i];
        if (f[i]) esum += expf(lg[i] - m);
    }
    red[threadIdx.x] = esum; __syncthreads();
    for (int s = 128; s; s >>= 1) {
        if (threadIdx.x < s) red[threadIdx.x] += red[threadIdx.x + s];
        __syncthreads();
    }
    float inv = 1.f / red[0];

    tsum[threadIdx.x] = s0; __syncthreads();
    for (int s = 1; s < 256; s <<= 1) {
        int u = (threadIdx.x >= s) ? tsum[threadIdx.x - s] : 0;
        __syncthreads();
        tsum[threadIdx.x] += u;
        __syncthreads();
    }
    int pos = tsum[threadIdx.x] - s0;
    for (int j = 0; j < 16; j++) {
        int i = threadIdx.x * 16 + j;
        if (f[i]) {
            rowidx[b * KSEL_ + pos] = b * S_ + i;
            rw[b * KSEL_ + pos] = expf(lg[i] - m) * inv;
            pos++;
        }
    }
}

// ---------------------------------------------------------------------------
// Aux loss: BCE-with-logits mean with flat-index union targets.
// ---------------------------------------------------------------------------
__global__ __launch_bounds__(256)
void loss_kernel(const float* __restrict__ logits, const int* __restrict__ flags,
                 float* __restrict__ partials) {
    __shared__ float red[256];
    int i = blockIdx.x * 256 + threadIdx.x;
    float l = logits[i];
    float t = 0.f;
    if (i < S_)
        t = (flags[i] | flags[S_ + i] | flags[2 * S_ + i] | flags[3 * S_ + i]) ? 1.f : 0.f;
    float v = fmaxf(l, 0.f) - l * t + log1pf(expf(-fabsf(l)));
    red[threadIdx.x] = v; __syncthreads();
    for (int s = 128; s; s >>= 1) {
        if (threadIdx.x < s) red[threadIdx.x] += red[threadIdx.x + s];
        __syncthreads();
    }
    if (threadIdx.x == 0) partials[blockIdx.x] = red[0];
}

__global__ void loss_final(const float* __restrict__ partials, float* __restrict__ out) {
    float v = partials[threadIdx.x];
#pragma unroll
    for (int s = 32; s; s >>= 1) v += __shfl_xor(v, s);
    if (threadIdx.x == 0) out[0] = v / (float)NTOK_;
}

// ---------------------------------------------------------------------------
// Pipelined GEMM: C[M=8192][N] = A(bf16) @ B, B given transposed BT[N][K].
// 128(M) x 256(N) tile, BK=64, 512 threads = 8 waves (2M x 4N), 64x64/wave.
// 3-slot LDS ring (144 KiB, 1 block/CU): iteration t stages K-tile t+2 into
// slot (t+2)%3 == (t-1)%3, whose readers finished at iteration t-1's barrier
// (stage issue is after that barrier in program order -> no write/read race).
// s_waitcnt vmcnt(6) before the raw s_barrier: tile t+1's 6 loads complete,
// tile t+2's 6 stay in flight across the barrier (counted vmcnt, T3+T4).
// Source-side XOR chunk swizzle keeps ds_read_b128 conflict-free (proven 0).
// MODE 1: H = silu(gather(A) @ W1), bf16. MODE 2: scatter x + (H@W2)*rw.
// ---------------------------------------------------------------------------
template <int MODE, int N, int K>
__global__ __launch_bounds__(512, 2)
void gemm_pipe_kernel(const unsigned short* __restrict__ A,
                      const unsigned short* __restrict__ BT,
                      const int* __restrict__ rowidx,
                      const float* __restrict__ rw,
                      const float* __restrict__ x,
                      unsigned short* __restrict__ Hout,
                      float* __restrict__ Out) {
    constexpr int BM = 128, BN = 256, BK = 64;
    constexpr int KI = K / BK;
    constexpr int NT = N / BN;
    constexpr int MT = M_ / BM;
    constexpr int NWG = NT * MT;
    constexpr int CPX = NWG / 8;          // NWG % 8 == 0 for both GEMMs
    __shared__ __attribute__((aligned(16))) unsigned short As[3][BM * BK];
    __shared__ __attribute__((aligned(16))) unsigned short Bs[3][BN * BK];

    const int tid = threadIdx.x;
    const int w = tid >> 6, lane = tid & 63;
    const int wm = w >> 2, wn = w & 3;

    // bijective XCD-aware swizzle: each XCD gets a contiguous x-fastest chunk
    int wgid = blockIdx.y * NT + blockIdx.x;
    int swz = (wgid & 7) * CPX + (wgid >> 3);
    const int tile_n = (swz % NT) * BN;
    const int tile_m = (swz / NT) * BM;

    // staging: lane -> row lane>>3 within an 8-row group; physical 16B chunk
    // lane&7 receives logical chunk (lane&7)^(row&7) (source-side swizzle).
    const int srow = lane >> 3;
    const int sw = (lane & 7) ^ srow;
    const uint64_t abase = (uint64_t)(uintptr_t)A;
    const uint64_t bbase = (uint64_t)(uintptr_t)BT;
    uint64_t aaddr[2], baddr[4];
#pragma unroll
    for (int t = 0; t < 2; ++t) {
        int r = t * 64 + w * 8 + srow;
        int ar = (MODE == 1) ? rowidx[tile_m + r] : (tile_m + r);
        aaddr[t] = abase + ((uint64_t)ar * K + (uint64_t)sw * 8) * 2ull;
    }
#pragma unroll
    for (int t = 0; t < 4; ++t) {
        int r = t * 64 + w * 8 + srow;
        baddr[t] = bbase + ((uint64_t)(tile_n + r) * K + (uint64_t)sw * 8) * 2ull;
    }

    auto stage = [&](int kt, int slot) {
        const uint64_t koff = (uint64_t)kt * (BK * 2);
#pragma unroll
        for (int t = 0; t < 2; ++t) {
            unsigned short* lds = &As[slot][(t * 64 + w * 8) * BK];
            __builtin_amdgcn_global_load_lds(
                (const __attribute__((address_space(1))) unsigned int*)(uintptr_t)(aaddr[t] + koff),
                (__attribute__((address_space(3))) unsigned int*)lds, 16, 0, 0);
        }
#pragma unroll
        for (int t = 0; t < 4; ++t) {
            unsigned short* lds = &Bs[slot][(t * 64 + w * 8) * BK];
            __builtin_amdgcn_global_load_lds(
                (const __attribute__((address_space(1))) unsigned int*)(uintptr_t)(baddr[t] + koff),
                (__attribute__((address_space(3))) unsigned int*)lds, 16, 0, 0);
        }
    };

    f32x4 acc[4][4];
#pragma unroll
    for (int i = 0; i < 4; i++)
#pragma unroll
        for (int j = 0; j < 4; j++) acc[i][j] = (f32x4){0.f, 0.f, 0.f, 0.f};

    // prologue: tiles 0,1 in flight; wait for tile 0 (12 outstanding -> <=6)
    stage(0, 0);
    stage(1, 1);
    asm volatile("s_waitcnt vmcnt(6)" ::: "memory");
    __builtin_amdgcn_s_barrier();

    const int lr = lane & 15, quad = lane >> 4;
    int s_cur = 0;
    for (int kt = 0; kt < KI; ++kt) {
        int s_pre = s_cur + 2; if (s_pre >= 3) s_pre -= 3;
        if (kt + 2 < KI) stage(kt + 2, s_pre);

        bf16x8 af[4][2], bfr[4][2];
#pragma unroll
        for (int m4 = 0; m4 < 4; ++m4) {
            int row = wm * 64 + m4 * 16 + lr;
#pragma unroll
            for (int ks = 0; ks < 2; ++ks) {
                int kc = ks * 4 + quad;
                af[m4][ks] = *(const bf16x8*)((const char*)&As[s_cur][0]
                                + row * (BK * 2) + ((kc ^ (lr & 7)) * 16));
            }
        }
#pragma unroll
        for (int n4 = 0; n4 < 4; ++n4) {
            int col = wn * 64 + n4 * 16 + lr;
#pragma unroll
            for (int ks = 0; ks < 2; ++ks) {
                int kc = ks * 4 + quad;
                bfr[n4][ks] = *(const bf16x8*)((const char*)&Bs[s_cur][0]
                                + col * (BK * 2) + ((kc ^ (lr & 7)) * 16));
            }
        }

        __builtin_amdgcn_s_setprio(1);
#pragma unroll
        for (int ks = 0; ks < 2; ++ks)
#pragma unroll
            for (int m4 = 0; m4 < 4; ++m4)
#pragma unroll
                for (int n4 = 0; n4 < 4; ++n4)
                    acc[m4][n4] = __builtin_amdgcn_mfma_f32_16x16x32_bf16(
                        af[m4][ks], bfr[n4][ks], acc[m4][n4], 0, 0, 0);
        __builtin_amdgcn_s_setprio(0);

        if (kt + 2 < KI) {
            asm volatile("s_waitcnt vmcnt(6)" ::: "memory");   // tile kt+1 ready
        } else {
            asm volatile("s_waitcnt vmcnt(0)" ::: "memory");   // tail drain
        }
        __builtin_amdgcn_s_barrier();
        s_cur += 1; if (s_cur >= 3) s_cur = 0;
    }

    if (MODE == 1) {
#pragma unroll
        for (int m4 = 0; m4 < 4; ++m4)
#pragma unroll
            for (int r = 0; r < 4; ++r) {
                int m = tile_m + wm * 64 + m4 * 16 + quad * 4 + r;
#pragma unroll
                for (int n4 = 0; n4 < 4; ++n4) {
                    int col = tile_n + wn * 64 + n4 * 16 + lr;
                    float v = acc[m4][n4][r];
                    v = v / (1.f + __expf(-v));   // silu
                    Hout[(uint64_t)m * N + col] = f2bf(v);
                }
            }
    } else {
#pragma unroll
        for (int m4 = 0; m4 < 4; ++m4)
#pragma unroll
            for (int r = 0; r < 4; ++r) {
                int m = tile_m + wm * 64 + m4 * 16 + quad * 4 + r;
                int grow = rowidx[m];
                float wgt = rw[m];
                uint64_t rb = (uint64_t)grow * D_;
#pragma unroll
                for (int n4 = 0; n4 < 4; ++n4) {
                    int col = tile_n + wn * 64 + n4 * 16 + lr;
                    Out[rb + col] = x[rb + col] + acc[m4][n4][r] * wgt;
                }
            }
    }
}

// ---------------------------------------------------------------------------
extern "C" void kernel_launch(void* const* d_in, const int* in_sizes, int n_in,
                              void* d_out, int out_size, void* d_ws, size_t ws_size,
                              hipStream_t stream) {
    const float* x  = (const float*)d_in[0];
    // d_in[1] = mask (unused: all-ones in setup, MLP ignores it)
    const float* Wr = (const float*)d_in[2];
    const float* W1 = (const float*)d_in[3];
    const float* W2 = (const float*)d_in[4];
    float* out = (float*)d_out;

    char* ws = (char*)d_ws;
    size_t off = 0;
    auto alloc = [&](size_t bytes) {
        char* p = ws + off;
        off = (off + bytes + 255) & ~(size_t)255;
        return p;
    };
    unsigned short* xb   = (unsigned short*)alloc((size_t)NTOK_ * D_ * 2);  // 33.5 MB
    unsigned short* W1bT = (unsigned short*)alloc((size_t)DFF_ * D_ * 2);   // 8.4 MB
    unsigned short* W2bT = (unsigned short*)alloc((size_t)D_ * DFF_ * 2);   // 8.4 MB
    unsigned short* H    = (unsigned short*)alloc((size_t)M_ * DFF_ * 2);   // 67 MB
    float* logits  = (float*)alloc(NTOK_ * 4);
    int*   rank    = (int*)alloc(NTOK_ * 4);
    int*   flags   = (int*)alloc(NTOK_ * 4);
    int*   rowidx  = (int*)alloc(M_ * 4);
    float* rwp     = (float*)alloc(M_ * 4);
    float* partials = (float*)alloc(64 * 4);

    (void)hipMemsetAsync(rank, 0, NTOK_ * 4, stream);

    transpose_bf16<<<dim3(DFF_ / 32, D_ / 32), dim3(32, 8), 0, stream>>>(W1, W1bT, D_, DFF_);
    transpose_bf16<<<dim3(D_ / 32, DFF_ / 32), dim3(32, 8), 0, stream>>>(W2, W2bT, DFF_, D_);
    router_kernel<<<NTOK_ / 4, 256, 0, stream>>>(x, Wr, logits, xb, out);
    rank_partial_kernel<<<512, 256, 0, stream>>>(logits, rank);
    compact_kernel<<<B_, 256, 0, stream>>>(logits, rank, flags, rowidx, rwp);
    loss_kernel<<<NTOK_ / 256, 256, 0, stream>>>(logits, flags, partials);
    loss_final<<<1, 64, 0, stream>>>(partials, out + (size_t)NTOK_ * D_);
    // GEMM1: H[8192][4096] = silu(gather(xb) @ W1)
    gemm_pipe_kernel<1, DFF_, D_><<<dim3(DFF_ / 256, M_ / 128), 512, 0, stream>>>(
        xb, W1bT, rowidx, nullptr, nullptr, H, nullptr);
    // GEMM2: out[rowidx[m]] = x[rowidx[m]] + (H @ W2)[m] * rw[m]
    gemm_pipe_kernel<2, D_, DFF_><<<dim3(D_ / 256, M_ / 128), 512, 0, stream>>>(
        H, W2bT, rowidx, rwp, x, nullptr, out);
}

// Round 4
// 361.881 us; speedup vs baseline: 1.0940x; 1.0940x over previous
//
#include <hip/hip_runtime.h>
#include <hip/hip_bf16.h>
#include <cstdint>

// Problem constants
#define B_ 4
#define S_ 4096
#define D_ 1024
#define DFF_ 4096
#define KSEL_ 2048
#define M_ (B_ * KSEL_)      // 8192 selected rows total
#define NTOK_ (B_ * S_)      // 16384

typedef short bf16x8 __attribute__((ext_vector_type(8)));
typedef float f32x4 __attribute__((ext_vector_type(4)));

__device__ inline unsigned short f2bf(float f) {
    union { float f; unsigned int u; } c; c.f = f;
    unsigned int u = c.u;
    unsigned int r = u + 0x7fffu + ((u >> 16) & 1u);
    return (unsigned short)(r >> 16);
}

// ---------------------------------------------------------------------------
// Transpose + fp32->bf16 convert: src [R][C] f32 -> dst [C][R] bf16
// ---------------------------------------------------------------------------
__global__ __launch_bounds__(256)
void transpose_bf16(const float* __restrict__ src, unsigned short* __restrict__ dst,
                    int R, int C) {
    __shared__ float tile[32][33];
    int c0 = blockIdx.x * 32, r0 = blockIdx.y * 32;
    for (int i = threadIdx.y; i < 32; i += 8)
        tile[i][threadIdx.x] = src[(size_t)(r0 + i) * C + c0 + threadIdx.x];
    __syncthreads();
    for (int i = threadIdx.y; i < 32; i += 8)
        dst[(size_t)(c0 + i) * R + r0 + threadIdx.x] = f2bf(tile[threadIdx.x][i]);
}

// ---------------------------------------------------------------------------
// Router: logits[row] = dot(x[row], Wr); write xb = bf16(x); write out = x
// ---------------------------------------------------------------------------
__global__ __launch_bounds__(256)
void router_kernel(const float* __restrict__ x, const float* __restrict__ Wr,
                   float* __restrict__ logits, unsigned short* __restrict__ xb,
                   float* __restrict__ out) {
    int wid = threadIdx.x >> 6, lane = threadIdx.x & 63;
    int row = blockIdx.x * 4 + wid;
    const float* xr = x + (size_t)row * D_;
    unsigned short* xbr = xb + (size_t)row * D_;
    float* outr = out + (size_t)row * D_;
    float acc = 0.f;
#pragma unroll
    for (int j = 0; j < 4; j++) {
        int off = j * 256 + lane * 4;
        float4 v = *(const float4*)(xr + off);
        float4 w = *(const float4*)(Wr + off);
        acc += v.x * w.x + v.y * w.y + v.z * w.z + v.w * w.w;
        *(float4*)(outr + off) = v;
        ushort4 o;
        o.x = f2bf(v.x); o.y = f2bf(v.y); o.z = f2bf(v.z); o.w = f2bf(v.w);
        *(ushort4*)(xbr + off) = o;
    }
#pragma unroll
    for (int s = 32; s; s >>= 1) acc += __shfl_xor(acc, s);
    if (lane == 0) logits[row] = acc;
}

// ---------------------------------------------------------------------------
// Rank (split-j): partial rank over a 512-logit j-chunk, atomicAdd into rank[].
// ---------------------------------------------------------------------------
__global__ __launch_bounds__(256)
void rank_partial_kernel(const float* __restrict__ logits, int* __restrict__ rank) {
    __shared__ float lj[512];
    int b  = blockIdx.x >> 7;
    int ic = (blockIdx.x >> 3) & 15;
    int jc = blockIdx.x & 7;
    const float* L = logits + b * S_;
    for (int t = threadIdx.x; t < 512; t += 256) lj[t] = L[jc * 512 + t];
    __syncthreads();
    int i = ic * 256 + threadIdx.x;
    float li = L[i];
    int jbase = jc * 512;
    int r = 0;
    const float4* __restrict__ lj4 = (const float4*)lj;
#pragma unroll 4
    for (int q = 0; q < 128; q++) {
        float4 v = lj4[q];
        int jb = jbase + q * 4;
        r += (v.x > li) | ((v.x == li) & (jb     < i));
        r += (v.y > li) | ((v.y == li) & (jb + 1 < i));
        r += (v.z > li) | ((v.z == li) & (jb + 2 < i));
        r += (v.w > li) | ((v.w == li) & (jb + 3 < i));
    }
    atomicAdd(&rank[b * S_ + i], r);
}

// ---------------------------------------------------------------------------
// Compact: sel = rank < KSEL_; flags, softmax weights, prefix-sum -> rowidx/rw.
// ---------------------------------------------------------------------------
__global__ __launch_bounds__(256)
void compact_kernel(const float* __restrict__ logits, const int* __restrict__ rank,
                    int* __restrict__ flags,
                    int* __restrict__ rowidx, float* __restrict__ rw) {
    __shared__ float lg[S_];
    __shared__ int f[S_];
    __shared__ int tsum[256];
    __shared__ float red[256];
    int b = blockIdx.x;
    const float* L = logits + b * S_;
    const int* R = rank + b * S_;
    int* F = flags + b * S_;
    for (int j = threadIdx.x; j < S_ / 4; j += 256) {
        ((float4*)lg)[j] = ((const float4*)L)[j];
        int4 rk = ((const int4*)R)[j];
        int4 fl;
        fl.x = rk.x < KSEL_; fl.y = rk.y < KSEL_;
        fl.z = rk.z < KSEL_; fl.w = rk.w < KSEL_;
        ((int4*)f)[j] = fl;
        ((int4*)F)[j] = fl;
    }
    __syncthreads();
    float mx = -INFINITY;
    for (int j = threadIdx.x; j < S_; j += 256) mx = fmaxf(mx, lg[j]);
    red[threadIdx.x] = mx; __syncthreads();
    for (int s = 128; s; s >>= 1) {
        if (threadIdx.x < s) red[threadIdx.x] = fmaxf(red[threadIdx.x], red[threadIdx.x + s]);
        __syncthreads();
    }
    float m = red[0];
    __syncthreads();

    float esum = 0.f;
    int s0 = 0;
#pragma unroll
    for (int j = 0; j < 16; j++) {
        int i = threadIdx.x * 16 + j;
        s0 += f[i];
        if (f[i]) esum += expf(lg[i] - m);
    }
    red[threadIdx.x] = esum; __syncthreads();
    for (int s = 128; s; s >>= 1) {
        if (threadIdx.x < s) red[threadIdx.x] += red[threadIdx.x + s];
        __syncthreads();
    }
    float inv = 1.f / red[0];

    tsum[threadIdx.x] = s0; __syncthreads();
    for (int s = 1; s < 256; s <<= 1) {
        int u = (threadIdx.x >= s) ? tsum[threadIdx.x - s] : 0;
        __syncthreads();
        tsum[threadIdx.x] += u;
        __syncthreads();
    }
    int pos = tsum[threadIdx.x] - s0;
    for (int j = 0; j < 16; j++) {
        int i = threadIdx.x * 16 + j;
        if (f[i]) {
            rowidx[b * KSEL_ + pos] = b * S_ + i;
            rw[b * KSEL_ + pos] = expf(lg[i] - m) * inv;
            pos++;
        }
    }
}

// ---------------------------------------------------------------------------
// Aux loss: BCE-with-logits mean with flat-index union targets.
// ---------------------------------------------------------------------------
__global__ __launch_bounds__(256)
void loss_kernel(const float* __restrict__ logits, const int* __restrict__ flags,
                 float* __restrict__ partials) {
    __shared__ float red[256];
    int i = blockIdx.x * 256 + threadIdx.x;
    float l = logits[i];
    float t = 0.f;
    if (i < S_)
        t = (flags[i] | flags[S_ + i] | flags[2 * S_ + i] | flags[3 * S_ + i]) ? 1.f : 0.f;
    float v = fmaxf(l, 0.f) - l * t + log1pf(expf(-fabsf(l)));
    red[threadIdx.x] = v; __syncthreads();
    for (int s = 128; s; s >>= 1) {
        if (threadIdx.x < s) red[threadIdx.x] += red[threadIdx.x + s];
        __syncthreads();
    }
    if (threadIdx.x == 0) partials[blockIdx.x] = red[0];
}

__global__ void loss_final(const float* __restrict__ partials, float* __restrict__ out) {
    float v = partials[threadIdx.x];
#pragma unroll
    for (int s = 32; s; s >>= 1) v += __shfl_xor(v, s);
    if (threadIdx.x == 0) out[0] = v / (float)NTOK_;
}

// ---------------------------------------------------------------------------
// Fine-phased pipelined GEMM (T3+T4+T5): C[M=8192][N] = A(bf16) @ BT[N][K].
// 128(M) x 256(N) tile, BK=64, 512 threads = 8 waves (2M x 4N), 64x64/wave.
// 3-slot LDS ring (144 KiB): during tile kt's phases we stage tile kt+2 into
// slot (kt+2)%3 == (kt-1)%3 (last read finished before kt-1's final barrier,
// stage issue is after it in program order -> race-free).
// Each K-tile = 2 phases (K-slice ks), each phase:
//   8 x ds_read_b128 (frags, XOR-swizzled: conflict-free, proven 0)
//   3 x global_load_lds issue (half of next+2 tile's 6 loads)
//   s_barrier ; s_waitcnt lgkmcnt(0) ; sched_barrier(0)   [rule 18]
//   s_setprio(1) ; 16 x mfma_16x16x32_bf16 ; s_setprio(0)
//   [end of phase 1 only] s_waitcnt vmcnt(6)  -- tile kt+1 complete,
//       tile kt+2's 6 loads stay in flight across the barrier (counted vmcnt)
//   s_barrier
// MODE 1: H = silu(gather(A) @ W1), bf16. MODE 2: scatter x + (H@W2)*rw.
// ---------------------------------------------------------------------------
template <int MODE, int N, int K>
__global__ __launch_bounds__(512, 2)
void gemm_pipe_kernel(const unsigned short* __restrict__ A,
                      const unsigned short* __restrict__ BT,
                      const int* __restrict__ rowidx,
                      const float* __restrict__ rw,
                      const float* __restrict__ x,
                      unsigned short* __restrict__ Hout,
                      float* __restrict__ Out) {
    constexpr int BM = 128, BN = 256, BK = 64;
    constexpr int KI = K / BK;
    constexpr int NT = N / BN;
    constexpr int MT = M_ / BM;
    constexpr int NWG = NT * MT;
    constexpr int CPX = NWG / 8;          // NWG % 8 == 0 for both GEMMs
    __shared__ __attribute__((aligned(16))) unsigned short As[3][BM * BK];
    __shared__ __attribute__((aligned(16))) unsigned short Bs[3][BN * BK];

    const int tid = threadIdx.x;
    const int w = tid >> 6, lane = tid & 63;
    const int wm = w >> 2, wn = w & 3;

    // bijective XCD-aware swizzle
    int wgid = blockIdx.y * NT + blockIdx.x;
    int swz = (wgid & 7) * CPX + (wgid >> 3);
    const int tile_n = (swz % NT) * BN;
    const int tile_m = (swz / NT) * BM;

    // staging: lane -> row lane>>3 within an 8-row group; physical 16B chunk
    // lane&7 receives logical chunk (lane&7)^(row&7) (source-side swizzle).
    const int srow = lane >> 3;
    const int sw = (lane & 7) ^ srow;
    const uint64_t abase = (uint64_t)(uintptr_t)A;
    const uint64_t bbase = (uint64_t)(uintptr_t)BT;
    uint64_t aaddr[2], baddr[4];
#pragma unroll
    for (int t = 0; t < 2; ++t) {
        int r = t * 64 + w * 8 + srow;
        int ar = (MODE == 1) ? rowidx[tile_m + r] : (tile_m + r);
        aaddr[t] = abase + ((uint64_t)ar * K + (uint64_t)sw * 8) * 2ull;
    }
#pragma unroll
    for (int t = 0; t < 4; ++t) {
        int r = t * 64 + w * 8 + srow;
        baddr[t] = bbase + ((uint64_t)(tile_n + r) * K + (uint64_t)sw * 8) * 2ull;
    }

    auto gload = [&](unsigned short* lds, uint64_t gaddr) {
        __builtin_amdgcn_global_load_lds(
            (const __attribute__((address_space(1))) unsigned int*)(uintptr_t)gaddr,
            (__attribute__((address_space(3))) unsigned int*)lds, 16, 0, 0);
    };

    auto stage_full = [&](int kt, int slot) {
        const uint64_t koff = (uint64_t)kt * (BK * 2);
#pragma unroll
        for (int t = 0; t < 2; ++t)
            gload(&As[slot][(t * 64 + w * 8) * BK], aaddr[t] + koff);
#pragma unroll
        for (int t = 0; t < 4; ++t)
            gload(&Bs[slot][(t * 64 + w * 8) * BK], baddr[t] + koff);
    };

    f32x4 acc[4][4];
#pragma unroll
    for (int i = 0; i < 4; i++)
#pragma unroll
        for (int j = 0; j < 4; j++) acc[i][j] = (f32x4){0.f, 0.f, 0.f, 0.f};

    // prologue: tiles 0,1 in flight; wait tile 0 (12 outstanding -> 6 left)
    stage_full(0, 0);
    stage_full(1, 1);
    asm volatile("s_waitcnt vmcnt(6)" ::: "memory");
    asm volatile("s_barrier" ::: "memory");

    const int lr = lane & 15, quad = lane >> 4;
    int c = 0;
    for (int kt = 0; kt < KI; ++kt) {
        int pre = c + 2; if (pre >= 3) pre -= 3;
        const char* Abase_l = (const char*)&As[c][0];
        const char* Bbase_l = (const char*)&Bs[c][0];
        const bool do_stage = (kt + 2 < KI);
        const uint64_t koff = (uint64_t)(kt + 2) * (BK * 2);

        // ================= phase 0 : ks = 0 =================
        {
            bf16x8 af[4], bfr[4];
            const int xo = (quad ^ (lr & 7)) * 16;       // kc = 0*4+quad
#pragma unroll
            for (int m4 = 0; m4 < 4; ++m4) {
                int row = wm * 64 + m4 * 16 + lr;
                af[m4] = *(const bf16x8*)(Abase_l + row * (BK * 2) + xo);
            }
#pragma unroll
            for (int n4 = 0; n4 < 4; ++n4) {
                int col = wn * 64 + n4 * 16 + lr;
                bfr[n4] = *(const bf16x8*)(Bbase_l + col * (BK * 2) + xo);
            }
            if (do_stage) {
#pragma unroll
                for (int t = 0; t < 2; ++t)
                    gload(&As[pre][(t * 64 + w * 8) * BK], aaddr[t] + koff);
                gload(&Bs[pre][(w * 8) * BK], baddr[0] + koff);
            }
            asm volatile("s_barrier" ::: "memory");
            asm volatile("s_waitcnt lgkmcnt(0)" ::: "memory");
            __builtin_amdgcn_sched_barrier(0);
            __builtin_amdgcn_s_setprio(1);
#pragma unroll
            for (int m4 = 0; m4 < 4; ++m4)
#pragma unroll
                for (int n4 = 0; n4 < 4; ++n4)
                    acc[m4][n4] = __builtin_amdgcn_mfma_f32_16x16x32_bf16(
                        af[m4], bfr[n4], acc[m4][n4], 0, 0, 0);
            __builtin_amdgcn_s_setprio(0);
            asm volatile("s_barrier" ::: "memory");
        }

        // ================= phase 1 : ks = 1 =================
        {
            bf16x8 af[4], bfr[4];
            const int xo = ((4 + quad) ^ (lr & 7)) * 16;  // kc = 1*4+quad
#pragma unroll
            for (int m4 = 0; m4 < 4; ++m4) {
                int row = wm * 64 + m4 * 16 + lr;
                af[m4] = *(const bf16x8*)(Abase_l + row * (BK * 2) + xo);
            }
#pragma unroll
            for (int n4 = 0; n4 < 4; ++n4) {
                int col = wn * 64 + n4 * 16 + lr;
                bfr[n4] = *(const bf16x8*)(Bbase_l + col * (BK * 2) + xo);
            }
            if (do_stage) {
#pragma unroll
                for (int t = 1; t < 4; ++t)
                    gload(&Bs[pre][(t * 64 + w * 8) * BK], baddr[t] + koff);
            }
            asm volatile("s_barrier" ::: "memory");
            asm volatile("s_waitcnt lgkmcnt(0)" ::: "memory");
            __builtin_amdgcn_sched_barrier(0);
            __builtin_amdgcn_s_setprio(1);
#pragma unroll
            for (int m4 = 0; m4 < 4; ++m4)
#pragma unroll
                for (int n4 = 0; n4 < 4; ++n4)
                    acc[m4][n4] = __builtin_amdgcn_mfma_f32_16x16x32_bf16(
                        af[m4], bfr[n4], acc[m4][n4], 0, 0, 0);
            __builtin_amdgcn_s_setprio(0);
            if (kt + 2 < KI) {
                asm volatile("s_waitcnt vmcnt(6)" ::: "memory");  // tile kt+1 done
            } else if (kt + 1 < KI) {
                asm volatile("s_waitcnt vmcnt(0)" ::: "memory");  // tail drain
            }
            asm volatile("s_barrier" ::: "memory");
        }

        c += 1; if (c >= 3) c = 0;
    }

    if (MODE == 1) {
#pragma unroll
        for (int m4 = 0; m4 < 4; ++m4)
#pragma unroll
            for (int r = 0; r < 4; ++r) {
                int m = tile_m + wm * 64 + m4 * 16 + quad * 4 + r;
#pragma unroll
                for (int n4 = 0; n4 < 4; ++n4) {
                    int col = tile_n + wn * 64 + n4 * 16 + lr;
                    float v = acc[m4][n4][r];
                    v = v / (1.f + __expf(-v));   // silu
                    Hout[(uint64_t)m * N + col] = f2bf(v);
                }
            }
    } else {
#pragma unroll
        for (int m4 = 0; m4 < 4; ++m4)
#pragma unroll
            for (int r = 0; r < 4; ++r) {
                int m = tile_m + wm * 64 + m4 * 16 + quad * 4 + r;
                int grow = rowidx[m];
                float wgt = rw[m];
                uint64_t rb = (uint64_t)grow * D_;
#pragma unroll
                for (int n4 = 0; n4 < 4; ++n4) {
                    int col = tile_n + wn * 64 + n4 * 16 + lr;
                    Out[rb + col] = x[rb + col] + acc[m4][n4][r] * wgt;
                }
            }
    }
}

// ---------------------------------------------------------------------------
extern "C" void kernel_launch(void* const* d_in, const int* in_sizes, int n_in,
                              void* d_out, int out_size, void* d_ws, size_t ws_size,
                              hipStream_t stream) {
    const float* x  = (const float*)d_in[0];
    // d_in[1] = mask (unused: all-ones in setup, MLP ignores it)
    const float* Wr = (const float*)d_in[2];
    const float* W1 = (const float*)d_in[3];
    const float* W2 = (const float*)d_in[4];
    float* out = (float*)d_out;

    char* ws = (char*)d_ws;
    size_t off = 0;
    auto alloc = [&](size_t bytes) {
        char* p = ws + off;
        off = (off + bytes + 255) & ~(size_t)255;
        return p;
    };
    unsigned short* xb   = (unsigned short*)alloc((size_t)NTOK_ * D_ * 2);  // 33.5 MB
    unsigned short* W1bT = (unsigned short*)alloc((size_t)DFF_ * D_ * 2);   // 8.4 MB
    unsigned short* W2bT = (unsigned short*)alloc((size_t)D_ * DFF_ * 2);   // 8.4 MB
    unsigned short* H    = (unsigned short*)alloc((size_t)M_ * DFF_ * 2);   // 67 MB
    float* logits  = (float*)alloc(NTOK_ * 4);
    int*   rank    = (int*)alloc(NTOK_ * 4);
    int*   flags   = (int*)alloc(NTOK_ * 4);
    int*   rowidx  = (int*)alloc(M_ * 4);
    float* rwp     = (float*)alloc(M_ * 4);
    float* partials = (float*)alloc(64 * 4);

    (void)hipMemsetAsync(rank, 0, NTOK_ * 4, stream);

    transpose_bf16<<<dim3(DFF_ / 32, D_ / 32), dim3(32, 8), 0, stream>>>(W1, W1bT, D_, DFF_);
    transpose_bf16<<<dim3(D_ / 32, DFF_ / 32), dim3(32, 8), 0, stream>>>(W2, W2bT, DFF_, D_);
    router_kernel<<<NTOK_ / 4, 256, 0, stream>>>(x, Wr, logits, xb, out);
    rank_partial_kernel<<<512, 256, 0, stream>>>(logits, rank);
    compact_kernel<<<B_, 256, 0, stream>>>(logits, rank, flags, rowidx, rwp);
    loss_kernel<<<NTOK_ / 256, 256, 0, stream>>>(logits, flags, partials);
    loss_final<<<1, 64, 0, stream>>>(partials, out + (size_t)NTOK_ * D_);
    // GEMM1: H[8192][4096] = silu(gather(xb) @ W1)
    gemm_pipe_kernel<1, DFF_, D_><<<dim3(DFF_ / 256, M_ / 128), 512, 0, stream>>>(
        xb, W1bT, rowidx, nullptr, nullptr, H, nullptr);
    // GEMM2: out[rowidx[m]] = x[rowidx[m]] + (H @ W2)[m] * rw[m]
    gemm_pipe_kernel<2, D_, DFF_><<<dim3(D_ / 256, M_ / 128), 512, 0, stream>>>(
        H, W2bT, rowidx, rwp, x, nullptr, out);
}

// Round 7
// 355.831 us; speedup vs baseline: 1.1126x; 1.0170x over previous
//
#include <hip/hip_runtime.h>
#include <hip/hip_bf16.h>
#include <cstdint>

// Problem constants
#define B_ 4
#define S_ 4096
#define D_ 1024
#define DFF_ 4096
#define KSEL_ 2048
#define M_ (B_ * KSEL_)      // 8192 selected rows total
#define NTOK_ (B_ * S_)      // 16384

typedef short bf16x8 __attribute__((ext_vector_type(8)));
typedef float f32x4 __attribute__((ext_vector_type(4)));

__device__ inline unsigned short f2bf(float f) {
    union { float f; unsigned int u; } c; c.f = f;
    unsigned int u = c.u;
    unsigned int r = u + 0x7fffu + ((u >> 16) & 1u);
    return (unsigned short)(r >> 16);
}

// ---------------------------------------------------------------------------
// Transpose + fp32->bf16 convert: src [R][C] f32 -> dst [C][R] bf16
// ---------------------------------------------------------------------------
__global__ __launch_bounds__(256)
void transpose_bf16(const float* __restrict__ src, unsigned short* __restrict__ dst,
                    int R, int C) {
    __shared__ float tile[32][33];
    int c0 = blockIdx.x * 32, r0 = blockIdx.y * 32;
    for (int i = threadIdx.y; i < 32; i += 8)
        tile[i][threadIdx.x] = src[(size_t)(r0 + i) * C + c0 + threadIdx.x];
    __syncthreads();
    for (int i = threadIdx.y; i < 32; i += 8)
        dst[(size_t)(c0 + i) * R + r0 + threadIdx.x] = f2bf(tile[threadIdx.x][i]);
}

// ---------------------------------------------------------------------------
// Router: logits[row] = dot(x[row], Wr); write xb = bf16(x); write out = x
// ---------------------------------------------------------------------------
__global__ __launch_bounds__(256)
void router_kernel(const float* __restrict__ x, const float* __restrict__ Wr,
                   float* __restrict__ logits, unsigned short* __restrict__ xb,
                   float* __restrict__ out) {
    int wid = threadIdx.x >> 6, lane = threadIdx.x & 63;
    int row = blockIdx.x * 4 + wid;
    const float* xr = x + (size_t)row * D_;
    unsigned short* xbr = xb + (size_t)row * D_;
    float* outr = out + (size_t)row * D_;
    float acc = 0.f;
#pragma unroll
    for (int j = 0; j < 4; j++) {
        int off = j * 256 + lane * 4;
        float4 v = *(const float4*)(xr + off);
        float4 w = *(const float4*)(Wr + off);
        acc += v.x * w.x + v.y * w.y + v.z * w.z + v.w * w.w;
        *(float4*)(outr + off) = v;
        ushort4 o;
        o.x = f2bf(v.x); o.y = f2bf(v.y); o.z = f2bf(v.z); o.w = f2bf(v.w);
        *(ushort4*)(xbr + off) = o;
    }
#pragma unroll
    for (int s = 32; s; s >>= 1) acc += __shfl_xor(acc, s);
    if (lane == 0) logits[row] = acc;
}

// ---------------------------------------------------------------------------
// Rank (split-j): partial rank over a 512-logit j-chunk, atomicAdd into rank[].
// ---------------------------------------------------------------------------
__global__ __launch_bounds__(256)
void rank_partial_kernel(const float* __restrict__ logits, int* __restrict__ rank) {
    __shared__ float lj[512];
    int b  = blockIdx.x >> 7;
    int ic = (blockIdx.x >> 3) & 15;
    int jc = blockIdx.x & 7;
    const float* L = logits + b * S_;
    for (int t = threadIdx.x; t < 512; t += 256) lj[t] = L[jc * 512 + t];
    __syncthreads();
    int i = ic * 256 + threadIdx.x;
    float li = L[i];
    int jbase = jc * 512;
    int r = 0;
    const float4* __restrict__ lj4 = (const float4*)lj;
#pragma unroll 4
    for (int q = 0; q < 128; q++) {
        float4 v = lj4[q];
        int jb = jbase + q * 4;
        r += (v.x > li) | ((v.x == li) & (jb     < i));
        r += (v.y > li) | ((v.y == li) & (jb + 1 < i));
        r += (v.z > li) | ((v.z == li) & (jb + 2 < i));
        r += (v.w > li) | ((v.w == li) & (jb + 3 < i));
    }
    atomicAdd(&rank[b * S_ + i], r);
}

// ---------------------------------------------------------------------------
// Compact: sel = rank < KSEL_; flags, softmax weights, prefix-sum -> rowidx/rw.
// ---------------------------------------------------------------------------
__global__ __launch_bounds__(256)
void compact_kernel(const float* __restrict__ logits, const int* __restrict__ rank,
                    int* __restrict__ flags,
                    int* __restrict__ rowidx, float* __restrict__ rw) {
    __shared__ float lg[S_];
    __shared__ int f[S_];
    __shared__ int tsum[256];
    __shared__ float red[256];
    int b = blockIdx.x;
    const float* L = logits + b * S_;
    const int* R = rank + b * S_;
    int* F = flags + b * S_;
    for (int j = threadIdx.x; j < S_ / 4; j += 256) {
        ((float4*)lg)[j] = ((const float4*)L)[j];
        int4 rk = ((const int4*)R)[j];
        int4 fl;
        fl.x = rk.x < KSEL_; fl.y = rk.y < KSEL_;
        fl.z = rk.z < KSEL_; fl.w = rk.w < KSEL_;
        ((int4*)f)[j] = fl;
        ((int4*)F)[j] = fl;
    }
    __syncthreads();
    float mx = -INFINITY;
    for (int j = threadIdx.x; j < S_; j += 256) mx = fmaxf(mx, lg[j]);
    red[threadIdx.x] = mx; __syncthreads();
    for (int s = 128; s; s >>= 1) {
        if (threadIdx.x < s) red[threadIdx.x] = fmaxf(red[threadIdx.x], red[threadIdx.x + s]);
        __syncthreads();
    }
    float m = red[0];
    __syncthreads();

    float esum = 0.f;
    int s0 = 0;
#pragma unroll
    for (int j = 0; j < 16; j++) {
        int i = threadIdx.x * 16 + j;
        s0 += f[i];
        if (f[i]) esum += expf(lg[i] - m);
    }
    red[threadIdx.x] = esum; __syncthreads();
    for (int s = 128; s; s >>= 1) {
        if (threadIdx.x < s) red[threadIdx.x] += red[threadIdx.x + s];
        __syncthreads();
    }
    float inv = 1.f / red[0];

    tsum[threadIdx.x] = s0; __syncthreads();
    for (int s = 1; s < 256; s <<= 1) {
        int u = (threadIdx.x >= s) ? tsum[threadIdx.x - s] : 0;
        __syncthreads();
        tsum[threadIdx.x] += u;
        __syncthreads();
    }
    int pos = tsum[threadIdx.x] - s0;
    for (int j = 0; j < 16; j++) {
        int i = threadIdx.x * 16 + j;
        if (f[i]) {
            rowidx[b * KSEL_ + pos] = b * S_ + i;
            rw[b * KSEL_ + pos] = expf(lg[i] - m) * inv;
            pos++;
        }
    }
}

// ---------------------------------------------------------------------------
// Aux loss: BCE-with-logits mean with flat-index union targets.
// ---------------------------------------------------------------------------
__global__ __launch_bounds__(256)
void loss_kernel(const float* __restrict__ logits, const int* __restrict__ flags,
                 float* __restrict__ partials) {
    __shared__ float red[256];
    int i = blockIdx.x * 256 + threadIdx.x;
    float l = logits[i];
    float t = 0.f;
    if (i < S_)
        t = (flags[i] | flags[S_ + i] | flags[2 * S_ + i] | flags[3 * S_ + i]) ? 1.f : 0.f;
    float v = fmaxf(l, 0.f) - l * t + log1pf(expf(-fabsf(l)));
    red[threadIdx.x] = v; __syncthreads();
    for (int s = 128; s; s >>= 1) {
        if (threadIdx.x < s) red[threadIdx.x] += red[threadIdx.x + s];
        __syncthreads();
    }
    if (threadIdx.x == 0) partials[blockIdx.x] = red[0];
}

__global__ void loss_final(const float* __restrict__ partials, float* __restrict__ out) {
    float v = partials[threadIdx.x];
#pragma unroll
    for (int s = 32; s; s >>= 1) v += __shfl_xor(v, s);
    if (threadIdx.x == 0) out[0] = v / (float)NTOK_;
}

// ---------------------------------------------------------------------------
// Fine-phased pipelined GEMM, persistent over SUBS M-tiles per block.
// C[M=8192][N] = A(bf16) @ BT[N][K].  128(M) x 256(N) tile, BK=64,
// 512 threads = 8 waves (2M x 4N), 64x64/wave.
// Grid = (N/256) x (M/(128*SUBS)) = 256 blocks for both GEMMs (1 block/CU).
// Each block runs ONE continuous 3-slot-ring pipeline over SUBS*KI K-steps;
// sub-tile boundaries only switch the A-row addresses (preloaded, statically
// indexed) and flush/zero the accumulator.  B panel (fixed n) stays L2-hot.
// Per K-step: 2 fine phases (T3+T5), counted vmcnt(6) at step end (T4):
//   phase: 8 ds_read_b128 (XOR-swizzled, conflict-free) ; 3 global_load_lds
//          (tile g+2 into slot (g+2)%3) ; s_barrier ; lgkmcnt(0) ;
//          sched_barrier(0) ; setprio(1) ; 16 MFMA ; setprio(0) ; [vmcnt] ;
//          s_barrier
// vmcnt accounting: mid-loop epilogues (MODE 1) issue only STORES, which are
// older than the 6 counted loads at the next vmcnt(6) -> forced complete,
// accounting exact.  All rowidx gathers preloaded before the prologue.
// MODE 1: H = silu(gather(A) @ W1), bf16. MODE 2: scatter x + (H@W2)*rw.
// ---------------------------------------------------------------------------
template <int MODE, int N, int K, int SUBS>
__global__ __launch_bounds__(512, 2)
void gemm_pipe_kernel(const unsigned short* __restrict__ A,
                      const unsigned short* __restrict__ BT,
                      const int* __restrict__ rowidx,
                      const float* __restrict__ rw,
                      const float* __restrict__ x,
                      unsigned short* __restrict__ Hout,
                      float* __restrict__ Out) {
    constexpr int BM = 128, BN = 256, BK = 64;
    constexpr int KI = K / BK;             // K-steps per sub-tile
    constexpr int NT = N / BN;
    constexpr int MG = M_ / (BM * SUBS);   // m-groups
    constexpr int NWG = NT * MG;           // 256 for both GEMMs
    constexpr int CPX = NWG / 8;
    __shared__ __attribute__((aligned(16))) unsigned short As[3][BM * BK];
    __shared__ __attribute__((aligned(16))) unsigned short Bs[3][BN * BK];

    const int tid = threadIdx.x;
    const int w = tid >> 6, lane = tid & 63;
    const int wm = w >> 2, wn = w & 3;

    // bijective XCD-aware swizzle
    int wgid = blockIdx.y * NT + blockIdx.x;
    int swz = (wgid & 7) * CPX + (wgid >> 3);
    const int tile_n = (swz % NT) * BN;
    const int mgrp   = (swz / NT);

    // staging: lane -> row lane>>3 within an 8-row group; physical 16B chunk
    // lane&7 receives logical chunk (lane&7)^(row&7) (source-side swizzle).
    const int srow = lane >> 3;
    const int sw = (lane & 7) ^ srow;
    const uint64_t abase = (uint64_t)(uintptr_t)A;
    const uint64_t bbase = (uint64_t)(uintptr_t)BT;
    uint64_t aaddr[SUBS][2], baddr[4];
#pragma unroll
    for (int s = 0; s < SUBS; ++s)
#pragma unroll
        for (int t = 0; t < 2; ++t) {
            int r = t * 64 + w * 8 + srow;
            int am = (mgrp * SUBS + s) * BM + r;
            int ar = (MODE == 1) ? rowidx[am] : am;
            aaddr[s][t] = abase + ((uint64_t)ar * K + (uint64_t)sw * 8) * 2ull;
        }
#pragma unroll
    for (int t = 0; t < 4; ++t) {
        int r = t * 64 + w * 8 + srow;
        baddr[t] = bbase + ((uint64_t)(tile_n + r) * K + (uint64_t)sw * 8) * 2ull;
    }

    auto gload = [&](unsigned short* lds, uint64_t gaddr) {
        __builtin_amdgcn_global_load_lds(
            (const __attribute__((address_space(1))) unsigned int*)(uintptr_t)gaddr,
            (__attribute__((address_space(3))) unsigned int*)lds, 16, 0, 0);
    };

    f32x4 acc[4][4];
#pragma unroll
    for (int i = 0; i < 4; i++)
#pragma unroll
        for (int j = 0; j < 4; j++) acc[i][j] = (f32x4){0.f, 0.f, 0.f, 0.f};

    // prologue: steps 0,1 (sub 0, kt 0,1) in flight; wait step 0 (12 -> 6)
#pragma unroll
    for (int p = 0; p < 2; ++p) {
        const uint64_t koff = (uint64_t)p * (BK * 2);
        gload(&As[p][(0 * 64 + w * 8) * BK], aaddr[0][0] + koff);
        gload(&As[p][(1 * 64 + w * 8) * BK], aaddr[0][1] + koff);
#pragma unroll
        for (int t = 0; t < 4; ++t)
            gload(&Bs[p][(t * 64 + w * 8) * BK], baddr[t] + koff);
    }
    asm volatile("s_waitcnt vmcnt(6)" ::: "memory");
    asm volatile("s_barrier" ::: "memory");

    const int lr = lane & 15, quad = lane >> 4;
    int c = 0;
#pragma unroll
    for (int s = 0; s < SUBS; ++s) {
#pragma unroll 1
        for (int kt = 0; kt < KI; ++kt) {
            int pre = c + 2; if (pre >= 3) pre -= 3;
            const char* Abase_l = (const char*)&As[c][0];
            const char* Bbase_l = (const char*)&Bs[c][0];
            const bool cross = (kt + 2 >= KI);
            const bool do_stage = (s < SUBS - 1) || (kt + 2 < KI);
            // statically-indexed address selection (rule #20: no runtime idx)
            const uint64_t sa0 = cross ? aaddr[(s + 1 < SUBS) ? s + 1 : s][0]
                                       : aaddr[s][0];
            const uint64_t sa1 = cross ? aaddr[(s + 1 < SUBS) ? s + 1 : s][1]
                                       : aaddr[s][1];
            const uint64_t koff = (uint64_t)((kt + 2) & (KI - 1)) * (BK * 2);

            // ================= phase 0 : ks = 0 =================
            {
                bf16x8 af[4], bfr[4];
                const int xo = (quad ^ (lr & 7)) * 16;       // kc = 0*4+quad
#pragma unroll
                for (int m4 = 0; m4 < 4; ++m4) {
                    int row = wm * 64 + m4 * 16 + lr;
                    af[m4] = *(const bf16x8*)(Abase_l + row * (BK * 2) + xo);
                }
#pragma unroll
                for (int n4 = 0; n4 < 4; ++n4) {
                    int col = wn * 64 + n4 * 16 + lr;
                    bfr[n4] = *(const bf16x8*)(Bbase_l + col * (BK * 2) + xo);
                }
                if (do_stage) {
                    gload(&As[pre][(0 * 64 + w * 8) * BK], sa0 + koff);
                    gload(&As[pre][(1 * 64 + w * 8) * BK], sa1 + koff);
                    gload(&Bs[pre][(w * 8) * BK], baddr[0] + koff);
                }
                asm volatile("s_barrier" ::: "memory");
                asm volatile("s_waitcnt lgkmcnt(0)" ::: "memory");
                __builtin_amdgcn_sched_barrier(0);
                __builtin_amdgcn_s_setprio(1);
#pragma unroll
                for (int m4 = 0; m4 < 4; ++m4)
#pragma unroll
                    for (int n4 = 0; n4 < 4; ++n4)
                        acc[m4][n4] = __builtin_amdgcn_mfma_f32_16x16x32_bf16(
                            af[m4], bfr[n4], acc[m4][n4], 0, 0, 0);
                __builtin_amdgcn_s_setprio(0);
                asm volatile("s_barrier" ::: "memory");
            }

            // ================= phase 1 : ks = 1 =================
            {
                bf16x8 af[4], bfr[4];
                const int xo = ((4 + quad) ^ (lr & 7)) * 16;  // kc = 1*4+quad
#pragma unroll
                for (int m4 = 0; m4 < 4; ++m4) {
                    int row = wm * 64 + m4 * 16 + lr;
                    af[m4] = *(const bf16x8*)(Abase_l + row * (BK * 2) + xo);
                }
#pragma unroll
                for (int n4 = 0; n4 < 4; ++n4) {
                    int col = wn * 64 + n4 * 16 + lr;
                    bfr[n4] = *(const bf16x8*)(Bbase_l + col * (BK * 2) + xo);
                }
                if (do_stage) {
#pragma unroll
                    for (int t = 1; t < 4; ++t)
                        gload(&Bs[pre][(t * 64 + w * 8) * BK], baddr[t] + koff);
                }
                asm volatile("s_barrier" ::: "memory");
                asm volatile("s_waitcnt lgkmcnt(0)" ::: "memory");
                __builtin_amdgcn_sched_barrier(0);
                __builtin_amdgcn_s_setprio(1);
#pragma unroll
                for (int m4 = 0; m4 < 4; ++m4)
#pragma unroll
                    for (int n4 = 0; n4 < 4; ++n4)
                        acc[m4][n4] = __builtin_amdgcn_mfma_f32_16x16x32_bf16(
                            af[m4], bfr[n4], acc[m4][n4], 0, 0, 0);
                __builtin_amdgcn_s_setprio(0);
                if (do_stage) {
                    asm volatile("s_waitcnt vmcnt(6)" ::: "memory"); // step g+1 done
                } else if (kt + 2 == KI) {
                    asm volatile("s_waitcnt vmcnt(0)" ::: "memory"); // tail drain
                }
                asm volatile("s_barrier" ::: "memory");
                c += 1; if (c >= 3) c = 0;
            }
        }

        // -------- sub-tile epilogue: flush acc, zero for next sub --------
        if (MODE == 1) {
            const int tile_m = (mgrp * SUBS + s) * BM;
#pragma unroll
            for (int m4 = 0; m4 < 4; ++m4)
#pragma unroll
                for (int r = 0; r < 4; ++r) {
                    int m = tile_m + wm * 64 + m4 * 16 + quad * 4 + r;
#pragma unroll
                    for (int n4 = 0; n4 < 4; ++n4) {
                        int col = tile_n + wn * 64 + n4 * 16 + lr;
                        float v = acc[m4][n4][r];
                        v = v / (1.f + __expf(-v));   // silu
                        Hout[(uint64_t)m * N + col] = f2bf(v);
                    }
                }
            if (s + 1 < SUBS) {
#pragma unroll
                for (int i = 0; i < 4; i++)
#pragma unroll
                    for (int j = 0; j < 4; j++)
                        acc[i][j] = (f32x4){0.f, 0.f, 0.f, 0.f};
            }
        }
    }

    if (MODE == 2) {
        const int tile_m = mgrp * SUBS * BM;   // SUBS == 1 for MODE 2
#pragma unroll
        for (int m4 = 0; m4 < 4; ++m4)
#pragma unroll
            for (int r = 0; r < 4; ++r) {
                int m = tile_m + wm * 64 + m4 * 16 + quad * 4 + r;
                int grow = rowidx[m];
                float wgt = rw[m];
                uint64_t rb = (uint64_t)grow * D_;
#pragma unroll
                for (int n4 = 0; n4 < 4; ++n4) {
                    int col = tile_n + wn * 64 + n4 * 16 + lr;
                    Out[rb + col] = x[rb + col] + acc[m4][n4][r] * wgt;
                }
            }
    }
}

// ---------------------------------------------------------------------------
extern "C" void kernel_launch(void* const* d_in, const int* in_sizes, int n_in,
                              void* d_out, int out_size, void* d_ws, size_t ws_size,
                              hipStream_t stream) {
    const float* x  = (const float*)d_in[0];
    // d_in[1] = mask (unused: all-ones in setup, MLP ignores it)
    const float* Wr = (const float*)d_in[2];
    const float* W1 = (const float*)d_in[3];
    const float* W2 = (const float*)d_in[4];
    float* out = (float*)d_out;

    char* ws = (char*)d_ws;
    size_t off = 0;
    auto alloc = [&](size_t bytes) {
        char* p = ws + off;
        off = (off + bytes + 255) & ~(size_t)255;
        return p;
    };
    unsigned short* xb   = (unsigned short*)alloc((size_t)NTOK_ * D_ * 2);  // 33.5 MB
    unsigned short* W1bT = (unsigned short*)alloc((size_t)DFF_ * D_ * 2);   // 8.4 MB
    unsigned short* W2bT = (unsigned short*)alloc((size_t)D_ * DFF_ * 2);   // 8.4 MB
    unsigned short* H    = (unsigned short*)alloc((size_t)M_ * DFF_ * 2);   // 67 MB
    float* logits  = (float*)alloc(NTOK_ * 4);
    int*   rank    = (int*)alloc(NTOK_ * 4);
    int*   flags   = (int*)alloc(NTOK_ * 4);
    int*   rowidx  = (int*)alloc(M_ * 4);
    float* rwp     = (float*)alloc(M_ * 4);
    float* partials = (float*)alloc(64 * 4);

    (void)hipMemsetAsync(rank, 0, NTOK_ * 4, stream);

    transpose_bf16<<<dim3(DFF_ / 32, D_ / 32), dim3(32, 8), 0, stream>>>(W1, W1bT, D_, DFF_);
    transpose_bf16<<<dim3(D_ / 32, DFF_ / 32), dim3(32, 8), 0, stream>>>(W2, W2bT, DFF_, D_);
    router_kernel<<<NTOK_ / 4, 256, 0, stream>>>(x, Wr, logits, xb, out);
    rank_partial_kernel<<<512, 256, 0, stream>>>(logits, rank);
    compact_kernel<<<B_, 256, 0, stream>>>(logits, rank, flags, rowidx, rwp);
    loss_kernel<<<NTOK_ / 256, 256, 0, stream>>>(logits, flags, partials);
    loss_final<<<1, 64, 0, stream>>>(partials, out + (size_t)NTOK_ * D_);
    // GEMM1: H[8192][4096] = silu(gather(xb) @ W1)  -- persistent, 4 M-tiles/block
    gemm_pipe_kernel<1, DFF_, D_, 4><<<dim3(DFF_ / 256, M_ / (128 * 4)), 512, 0, stream>>>(
        xb, W1bT, rowidx, nullptr, nullptr, H, nullptr);
    // GEMM2: out[rowidx[m]] = x[rowidx[m]] + (H @ W2)[m] * rw[m]
    gemm_pipe_kernel<2, D_, DFF_, 1><<<dim3(D_ / 256, M_ / 128), 512, 0, stream>>>(
        H, W2bT, rowidx, rwp, x, nullptr, out);
}